// Round 1
// baseline (4467.701 us; speedup 1.0000x reference)
//
#include <hip/hip_runtime.h>
#include <math.h>

#define B 128
#define H 32
#define D 128
#define S 64
#define T0 32
#define SCALE 0.125f

#define NB 2            // (b,h) pairs per workgroup (same head h)
#define TPP 256         // threads per pair
#define NTHREADS (NB*TPP)
#define KV_STRIDE 129   // +1 pad: attn reads row s at lane s -> (s+d)%32 banks, 2-way max

// LDS layout (floats):
//   Kl [NB][S][129], Vl [NB][S][129], xv [NB][128], xq [NB][128],
//   red [NB][768], attnp [NB][64]
#define LDS_FLOATS (2*NB*S*KV_STRIDE + NB*D + NB*D + NB*3*D*2 + NB*S)
#define LDS_BYTES (LDS_FLOATS*4)

__global__ void __launch_bounds__(NTHREADS, 1)
attn_decode_kernel(const float* __restrict__ x_in,
                   const float* __restrict__ k_in,
                   const float* __restrict__ v_in,
                   const float* __restrict__ wq,
                   const float* __restrict__ wk,
                   const float* __restrict__ wv,
                   const float* __restrict__ wo,
                   float* __restrict__ out)
{
    extern __shared__ float smem[];
    float* Kl    = smem;                      // [NB][S][KV_STRIDE]
    float* Vl    = Kl + NB*S*KV_STRIDE;
    float* xv    = Vl + NB*S*KV_STRIDE;       // [NB][D] current x
    float* xq    = xv + NB*D;                 // [NB][D] q, then x_new
    float* red   = xq + NB*D;                 // [NB][768] scratch
    float* attnp = red + NB*3*D*2;            // [NB][S]

    const int j    = threadIdx.x;
    const int pair = j >> 8;                  // 0..NB-1
    const int tid  = j & 255;                 // 0..255 within pair
    const int pglob = blockIdx.x * NB + pair; // pair index = h*B + b
    const int h = pglob / B;
    const int b = pglob % B;

    const float* wqh = wq + h*D*D;
    const float* wkh = wk + h*D*D;
    const float* wvh = wv + h*D*D;
    const float* woh = wo + h*D*D;

    // ---- load K/V cache and x into LDS (float4 global loads) ----
    const float* kg = k_in + (size_t)(b*H + h)*S*D;
    const float* vg = v_in + (size_t)(b*H + h)*S*D;
    for (int i = tid; i < S*D/4; i += TPP) {
        int s  = i >> 5;            // / (D/4)
        int dq = (i & 31) << 2;
        float4 k4 = reinterpret_cast<const float4*>(kg)[i];
        float4 v4 = reinterpret_cast<const float4*>(vg)[i];
        float* kr = &Kl[(pair*S + s)*KV_STRIDE + dq];
        kr[0]=k4.x; kr[1]=k4.y; kr[2]=k4.z; kr[3]=k4.w;
        float* vr = &Vl[(pair*S + s)*KV_STRIDE + dq];
        vr[0]=v4.x; vr[1]=v4.y; vr[2]=v4.z; vr[3]=v4.w;
    }
    if (tid < D) xv[pair*D + tid] = x_in[(size_t)(b*H + h)*D + tid];
    __syncthreads();

    const int col = tid & 127;     // output column (phases 1,4,5)
    const int dh  = tid >> 7;      // 0/1: which half of d (phases 1,5)
    const int s64 = tid & 63;      // score row (phase 2)
    const int dq4 = tid >> 6;      // 0..3: quarter of d (phase 2)

    float* redp = red + pair*768;

    for (int t = T0; t < S; ++t) {
        // ---- phase 1: q/k/v projections (fused 3-matvec, split-d) ----
        {
            float aq = 0.f, ak = 0.f, av = 0.f;
            const float* xp = xv + pair*D;
            #pragma unroll 8
            for (int i = 0; i < 64; ++i) {
                int d = dh*64 + i;
                float xd = xp[d];                // LDS broadcast within wave
                int idx = d*D + col;             // coalesced weight stream
                aq = fmaf(xd, wqh[idx], aq);
                ak = fmaf(xd, wkh[idx], ak);
                av = fmaf(xd, wvh[idx], av);
            }
            redp[0*2*D + dh*D + col] = aq;       // banks: col%32, 2-way
            redp[1*2*D + dh*D + col] = ak;
            redp[2*2*D + dh*D + col] = av;
        }
        __syncthreads();
        if (tid < D) {
            float qv = redp[0*2*D + tid] + redp[0*2*D + D + tid];
            float kv = redp[1*2*D + tid] + redp[1*2*D + D + tid];
            float vv = redp[2*2*D + tid] + redp[2*2*D + D + tid];
            xq[pair*D + tid] = qv;
            Kl[(pair*S + t)*KV_STRIDE + tid] = kv;  // scatter BEFORE attention
            Vl[(pair*S + t)*KV_STRIDE + tid] = vv;
        }
        __syncthreads();

        // ---- phase 2: attn scores q.K^T ----
        {
            float a = 0.f;
            const float* qp = xq + pair*D;
            const float* kr = &Kl[(pair*S + s64)*KV_STRIDE];
            #pragma unroll 8
            for (int i = 0; i < 32; ++i) {
                int d = dq4*32 + i;
                a = fmaf(qp[d], kr[d], a);       // (s+d)%32 banks: 2-way
            }
            redp[dq4*64 + s64] = a;
        }
        __syncthreads();

        // ---- phase 3: softmax over S=64, one full wave per pair ----
        if (tid < 64) {
            float a = (redp[tid] + redp[64 + tid] + redp[128 + tid] + redp[192 + tid]) * SCALE;
            float m = a;
            #pragma unroll
            for (int msk = 32; msk; msk >>= 1)
                m = fmaxf(m, __shfl_xor(m, msk));
            float e = expf(a - m);
            float ssum = e;
            #pragma unroll
            for (int msk = 32; msk; msk >>= 1)
                ssum += __shfl_xor(ssum, msk);
            attnp[pair*S + tid] = e / ssum;
        }
        __syncthreads();

        // ---- phase 4: x_new = P.V (split-s) ----
        {
            float a = 0.f;
            const float* pp = attnp + pair*S;
            #pragma unroll 8
            for (int i = 0; i < 32; ++i) {
                int s = dh*32 + i;
                a = fmaf(pp[s], Vl[(pair*S + s)*KV_STRIDE + col], a);
            }
            redp[dh*D + col] = a;
        }
        __syncthreads();
        if (tid < D) xq[pair*D + tid] = redp[tid] + redp[D + tid];
        __syncthreads();

        // ---- phase 5: O projection ----
        {
            float a = 0.f;
            const float* xp = xq + pair*D;
            #pragma unroll 8
            for (int i = 0; i < 64; ++i) {
                int d = dh*64 + i;
                a = fmaf(xp[d], woh[d*D + col], a);
            }
            redp[dh*D + col] = a;
        }
        __syncthreads();
        if (tid < D) xv[pair*D + tid] = redp[tid] + redp[D + tid];
        __syncthreads();
    }

    // ---- write outputs: k cache, v cache, final x ----
    float* kout = out + (size_t)(b*H + h)*S*D;
    float* vout = out + (size_t)B*H*S*D + (size_t)(b*H + h)*S*D;
    float* xout = out + (size_t)2*B*H*S*D + (size_t)(b*H + h)*D;
    for (int i = tid; i < S*D/4; i += TPP) {
        int s  = i >> 5;
        int dq = (i & 31) << 2;
        const float* kr = &Kl[(pair*S + s)*KV_STRIDE + dq];
        reinterpret_cast<float4*>(kout)[i] = make_float4(kr[0], kr[1], kr[2], kr[3]);
        const float* vr = &Vl[(pair*S + s)*KV_STRIDE + dq];
        reinterpret_cast<float4*>(vout)[i] = make_float4(vr[0], vr[1], vr[2], vr[3]);
    }
    if (tid < D) xout[tid] = xv[pair*D + tid];
}

extern "C" void kernel_launch(void* const* d_in, const int* in_sizes, int n_in,
                              void* d_out, int out_size, void* d_ws, size_t ws_size,
                              hipStream_t stream) {
    (void)in_sizes; (void)n_in; (void)out_size; (void)d_ws; (void)ws_size;
    const float* x  = (const float*)d_in[0];
    const float* k  = (const float*)d_in[1];
    const float* v  = (const float*)d_in[2];
    const float* wq = (const float*)d_in[3];
    const float* wk = (const float*)d_in[4];
    const float* wv = (const float*)d_in[5];
    const float* wo = (const float*)d_in[6];
    float* out = (float*)d_out;

    // >64KB dynamic LDS needs the opt-in attribute (idempotent, not a stream op:
    // safe under graph capture).
    hipFuncSetAttribute(reinterpret_cast<const void*>(attn_decode_kernel),
                        hipFuncAttributeMaxDynamicSharedMemorySize, LDS_BYTES);

    dim3 grid(B*H/NB);   // 2048 workgroups, pair index = h*B + b (both pairs share h)
    dim3 block(NTHREADS);
    attn_decode_kernel<<<grid, block, LDS_BYTES, stream>>>(x, k, v, wq, wk, wv, wo, out);
}

// Round 2
// 1211.048 us; speedup vs baseline: 3.6891x; 3.6891x over previous
//
#include <hip/hip_runtime.h>
#include <math.h>

#define B 128
#define H 32
#define D 128
#define S 64
#define T0 32
#define SCALE 0.125f

#define NB 2            // (b,h) pairs per workgroup (same head h)
#define NT 512
#define KVS 132         // K/V row stride (floats): 16B-aligned, non-pow2 -> b128 at bank floor

// LDS layout (floats)
#define OFF_KL 0
#define OFF_VL (OFF_KL + NB*S*KVS)
#define OFF_X2 (OFF_VL + NB*S*KVS)          // x interleaved [d][pair]
#define OFF_QB (OFF_X2 + 256)               // q plain [pair][128]
#define OFF_XO (OFF_QB + 256)               // attn-out interleaved [d][pair]
#define OFF_RED (OFF_XO + 256)              // scratch, 4096 floats
#define OFF_AT (OFF_RED + 4096)             // attn probs [pair][64]
#define LDS_FLOATS (OFF_AT + 128)
#define LDS_BYTES (LDS_FLOATS*4)            // 155,136 B <= 160 KiB

__global__ void __launch_bounds__(NT, 2)
attn_decode_kernel(const float* __restrict__ x_in,
                   const float* __restrict__ k_in,
                   const float* __restrict__ v_in,
                   const float* __restrict__ wq,
                   const float* __restrict__ wk,
                   const float* __restrict__ wv,
                   const float* __restrict__ wo,
                   float* __restrict__ out)
{
    extern __shared__ float smem[];
    float* Kl    = smem + OFF_KL;
    float* Vl    = smem + OFF_VL;
    float* x2    = smem + OFF_X2;
    float* qb    = smem + OFF_QB;
    float* xo2   = smem + OFF_XO;
    float* red   = smem + OFF_RED;
    float* attnp = smem + OFF_AT;

    const int tid = threadIdx.x;
    // XCD-aware swizzle: 2048 WGs, 8 XCDs -> each XCD gets 256 contiguous
    // logical WGs = 4 heads -> 1MB of weights resident per XCD L2.
    const int blk = (blockIdx.x & 7) * 256 + (blockIdx.x >> 3);
    const int h  = blk >> 6;          // 64 WGs per head
    const int b0 = (blk & 63) << 1;   // pair p handles batch b0+p

    // ---- weight ownership ----
    // QKV (tid<384): matrix m = tid>>7 (waves 0,1=q 2,3=k 4,5=v), dq = d-quarter,
    // cg = 4-column group. Each owns W[d=dq*32+i][cg*4..+3], i<32 -> 32 float4.
    const int m  = tid >> 7;
    const int dq = (tid >> 5) & 3;
    const int cg = tid & 31;
    // O-proj (all 512): ds = d-sixteenth (8 rows each), same cg -> 8 float4.
    const int ds = tid >> 5;

    float4 w[32];
    if (m < 3) {
        const float* Wm = (m == 0 ? wq : (m == 1 ? wk : wv)) + h*D*D + (dq*32)*D + cg*4;
        #pragma unroll
        for (int i = 0; i < 32; ++i)
            w[i] = *reinterpret_cast<const float4*>(Wm + i*D);
    }
    float4 wob[8];
    {
        const float* Wo = wo + h*D*D + (ds*8)*D + cg*4;
        #pragma unroll
        for (int i = 0; i < 8; ++i)
            wob[i] = *reinterpret_cast<const float4*>(Wo + i*D);
    }

    // ---- stage K/V cache + x into LDS ----
    for (int i = tid; i < NB*S*(D/4); i += NT) {
        int p = i >> 11, s = (i >> 5) & 63, g = i & 31;
        size_t base = (size_t)((b0+p)*H + h) * S * D;
        float4 k4 = reinterpret_cast<const float4*>(k_in + base)[s*32 + g];
        float4 v4 = reinterpret_cast<const float4*>(v_in + base)[s*32 + g];
        *reinterpret_cast<float4*>(&Kl[(p*S + s)*KVS + g*4]) = k4;
        *reinterpret_cast<float4*>(&Vl[(p*S + s)*KVS + g*4]) = v4;
    }
    if (tid < 256) {
        int p = tid >> 7, d = tid & 127;
        x2[d*2 + p] = x_in[(size_t)((b0+p)*H + h)*D + d];
    }
    __syncthreads();

    for (int t = T0; t < S; ++t) {
        // ---- phase 1: QKV projection partials (waves 0-5) ----
        if (m < 3) {
            float4 a0 = {0,0,0,0}, a1 = {0,0,0,0};
            #pragma unroll
            for (int i = 0; i < 32; ++i) {
                float2 xd = *reinterpret_cast<const float2*>(&x2[(dq*32 + i)*2]);
                a0.x = fmaf(xd.x, w[i].x, a0.x); a0.y = fmaf(xd.x, w[i].y, a0.y);
                a0.z = fmaf(xd.x, w[i].z, a0.z); a0.w = fmaf(xd.x, w[i].w, a0.w);
                a1.x = fmaf(xd.y, w[i].x, a1.x); a1.y = fmaf(xd.y, w[i].y, a1.y);
                a1.z = fmaf(xd.y, w[i].z, a1.z); a1.w = fmaf(xd.y, w[i].w, a1.w);
            }
            *reinterpret_cast<float4*>(&red[((m*4 + dq)*2 + 0)*128 + cg*4]) = a0;
            *reinterpret_cast<float4*>(&red[((m*4 + dq)*2 + 1)*128 + cg*4]) = a1;
        }
        __syncthreads();
        // reduce 4 partials; scatter k/v row t into cache; store q
        for (int u = tid; u < 768; u += NT) {
            int mm = u >> 8, p = (u >> 7) & 1, col = u & 127;
            float sm = red[((mm*4+0)*2+p)*128+col] + red[((mm*4+1)*2+p)*128+col]
                     + red[((mm*4+2)*2+p)*128+col] + red[((mm*4+3)*2+p)*128+col];
            if (mm == 0)      qb[p*128 + col] = sm;
            else if (mm == 1) Kl[(p*S + t)*KVS + col] = sm;
            else              Vl[(p*S + t)*KVS + col] = sm;
        }
        __syncthreads();

        // ---- phase 2: scores q.K^T (all 512: pair x 64 rows x 4 d-quarters) ----
        {
            int p = tid >> 8, dqq = (tid >> 6) & 3, s = tid & 63;
            const float* kr = &Kl[(p*S + s)*KVS + dqq*32];
            const float* qr = &qb[p*128 + dqq*32];
            float acc = 0.f;
            #pragma unroll
            for (int j = 0; j < 8; ++j) {
                float4 kk = *reinterpret_cast<const float4*>(kr + j*4);
                float4 qq = *reinterpret_cast<const float4*>(qr + j*4);
                acc = fmaf(kk.x, qq.x, fmaf(kk.y, qq.y, fmaf(kk.z, qq.z, fmaf(kk.w, qq.w, acc))));
            }
            red[(p*4 + dqq)*64 + s] = acc;
        }
        __syncthreads();

        // ---- phase 3: softmax (waves 0-1, one wave per pair) ----
        if (tid < 128) {
            int p = tid >> 6, s = tid & 63;
            float a = (red[(p*4+0)*64+s] + red[(p*4+1)*64+s]
                     + red[(p*4+2)*64+s] + red[(p*4+3)*64+s]) * SCALE;
            float mx = a;
            #pragma unroll
            for (int k2 = 32; k2; k2 >>= 1) mx = fmaxf(mx, __shfl_xor(mx, k2));
            float e = expf(a - mx);
            float ssum = e;
            #pragma unroll
            for (int k2 = 32; k2; k2 >>= 1) ssum += __shfl_xor(ssum, k2);
            attnp[p*64 + s] = e / ssum;
        }
        __syncthreads();

        // ---- phase 4: PV (all 512: pair x 128 cols x 2 s-halves) ----
        {
            int p = tid >> 8, sh = (tid >> 7) & 1, col = tid & 127;
            const float* pp = &attnp[p*64 + sh*32];
            float acc = 0.f;
            #pragma unroll
            for (int i = 0; i < 32; ++i)
                acc = fmaf(pp[i], Vl[(p*S + sh*32 + i)*KVS + col], acc);
            red[(p*2 + sh)*128 + col] = acc;
        }
        __syncthreads();
        if (tid < 256) {
            int p = tid >> 7, col = tid & 127;
            xo2[col*2 + p] = red[(p*2+0)*128+col] + red[(p*2+1)*128+col];
        }
        __syncthreads();

        // ---- phase 5: O projection (all 512: 32 cg x 16 d-slices) ----
        {
            float4 a0 = {0,0,0,0}, a1 = {0,0,0,0};
            #pragma unroll
            for (int i = 0; i < 8; ++i) {
                float2 xd = *reinterpret_cast<const float2*>(&xo2[(ds*8 + i)*2]);
                a0.x = fmaf(xd.x, wob[i].x, a0.x); a0.y = fmaf(xd.x, wob[i].y, a0.y);
                a0.z = fmaf(xd.x, wob[i].z, a0.z); a0.w = fmaf(xd.x, wob[i].w, a0.w);
                a1.x = fmaf(xd.y, wob[i].x, a1.x); a1.y = fmaf(xd.y, wob[i].y, a1.y);
                a1.z = fmaf(xd.y, wob[i].z, a1.z); a1.w = fmaf(xd.y, wob[i].w, a1.w);
            }
            *reinterpret_cast<float4*>(&red[(ds*2 + 0)*128 + cg*4]) = a0;
            *reinterpret_cast<float4*>(&red[(ds*2 + 1)*128 + cg*4]) = a1;
        }
        __syncthreads();
        if (tid < 256) {
            int p = tid >> 7, col = tid & 127;
            float sm = 0.f;
            #pragma unroll
            for (int d16 = 0; d16 < 16; ++d16) sm += red[(d16*2 + p)*128 + col];
            x2[col*2 + p] = sm;
        }
        __syncthreads();
    }

    // ---- outputs: k cache, v cache, final x ----
    float* kout = out;
    float* vout = out + (size_t)B*H*S*D;
    float* xout = out + (size_t)2*B*H*S*D;
    for (int i = tid; i < NB*S*(D/4); i += NT) {
        int p = i >> 11, s = (i >> 5) & 63, g = i & 31;
        size_t base = (size_t)((b0+p)*H + h) * S * D;
        float4 k4 = *reinterpret_cast<const float4*>(&Kl[(p*S + s)*KVS + g*4]);
        float4 v4 = *reinterpret_cast<const float4*>(&Vl[(p*S + s)*KVS + g*4]);
        reinterpret_cast<float4*>(kout + base)[s*32 + g] = k4;
        reinterpret_cast<float4*>(vout + base)[s*32 + g] = v4;
    }
    if (tid < 256) {
        int p = tid >> 7, d = tid & 127;
        xout[(size_t)((b0+p)*H + h)*D + d] = x2[d*2 + p];
    }
}

extern "C" void kernel_launch(void* const* d_in, const int* in_sizes, int n_in,
                              void* d_out, int out_size, void* d_ws, size_t ws_size,
                              hipStream_t stream) {
    (void)in_sizes; (void)n_in; (void)out_size; (void)d_ws; (void)ws_size;
    const float* x  = (const float*)d_in[0];
    const float* k  = (const float*)d_in[1];
    const float* v  = (const float*)d_in[2];
    const float* wq = (const float*)d_in[3];
    const float* wk = (const float*)d_in[4];
    const float* wv = (const float*)d_in[5];
    const float* wo = (const float*)d_in[6];
    float* out = (float*)d_out;

    hipFuncSetAttribute(reinterpret_cast<const void*>(attn_decode_kernel),
                        hipFuncAttributeMaxDynamicSharedMemorySize, LDS_BYTES);

    dim3 grid(B*H/NB);   // 2048 WGs
    dim3 block(NT);
    attn_decode_kernel<<<grid, block, LDS_BYTES, stream>>>(x, k, v, wq, wk, wv, wo, out);
}